// Round 1
// 176.582 us; speedup vs baseline: 1.0080x; 1.0080x over previous
//
#include <hip/hip_runtime.h>
#include <math.h>

#define G_MAX 512   // LDS capacity for GT boxes; setup uses G=300
#define SPLIT 4     // threads per anchor (g-loop split)

__device__ __forceinline__ float waveSum(float v) {
#pragma unroll
  for (int o = 32; o > 0; o >>= 1) v += __shfl_down(v, o, 64);
  return v;
}

// smooth-L1 with sigma=3 (s2=9)
__device__ __forceinline__ float huber9(float x) {
  float ax = fabsf(x);
  return (ax < (1.0f / 9.0f)) ? 4.5f * x * x : ax - (0.5f / 9.0f);
}

// Exact IoU in the reference's op order. g = (x0, y0, x1+1, y1+1)
__device__ __forceinline__ float iouExact(float bx0, float by0, float bx1, float by1,
                                          float areab, float4 g, float areag) {
  float gx1 = g.z - 1.0f, gy1 = g.w - 1.0f;  // exact inverse of the staged +1
  float iw = fminf(bx1, gx1) - fmaxf(bx0, g.x) + 1.0f;
  float ih = fminf(by1, gy1) - fmaxf(by0, g.y) + 1.0f;
  float inter = fmaxf(iw, 0.f) * fmaxf(ih, 0.f);
  float uni = areab + areag - inter;
  return inter / fmaxf(uni, 1.0f);
}

// Inverse comparison key: key = (areaB+areaG)*rcp(inter); argmax iou == argmin
// key (uint compare on positive floats). ONE-CLAMP trick: inter = max(iw,0)*ih.
//   ih >= 0: identical to the two-clamp value (positive-overlap keys exact).
//   ih <  0: inter <= -0 -> key negative or -inf -> uint >= 0x80000000 ->
//            ranks below ALL positive keys under min-tracking, i.e. in the
//            zero-overlap class, whose internal order is output-invariant
//            (winners are recomputed exactly with validity masks; all
//            zero-overlap/invalid picks yield label 0 / fg=false / value 0).
// Low 9 bits carry g: min-ties resolve to smallest g (jax stable semantics).
// Never NaN: S>0 finite, S*(+-inf)=+-inf.
__device__ __forceinline__ uint32_t packKey(float x0, float y0, float x1p, float y1p,
                                            float area, float4 gb, float ga,
                                            uint32_t g) {
  float iw = fminf(x1p, gb.z) - fmaxf(x0, gb.x);
  float ih = fminf(y1p, gb.w) - fmaxf(y0, gb.y);
  float inter = fmaxf(iw, 0.f) * ih;
  float key = (area + ga) * __builtin_amdgcn_rcpf(inter);
  return (__float_as_uint(key) & 0xFFFFFE00u) | g;
}

__global__ __launch_bounds__(256) void retina_main(
    const float* __restrict__ pred_cls,   // (n, A, 2)
    const float* __restrict__ rpn_num,    // (n, A, 2)
    const float* __restrict__ pred_reg,   // (n, A, 8)
    const float* __restrict__ anchors,    // (A, 4)
    const float* __restrict__ rpn_iou,    // (n, A, 2)
    const float* __restrict__ boxes,      // (n, G, 5)
    int A, int G, int totalBlocks,
    double* __restrict__ acc,             // 7 accumulators, stride 16 doubles
    unsigned int* __restrict__ cnt,       // ticket counter (zeroed)
    float* __restrict__ out)              // 4 floats
{
  __shared__ float4 sBox[G_MAX];  // x0, y0, x1+1, y1+1
  __shared__ float sA[G_MAX];     // area (1e30 for invalid/dummy)
  __shared__ float sRed[4][7];
  __shared__ float sStash[64][10];      // decoded boxes of needy anchors (by slot)
  __shared__ float2 sRes[64];           // aval/bval results (by anchor-local al)
  __shared__ unsigned char sList[64];   // slot -> al
  __shared__ int sLast;
  __shared__ int sNum;

  const int img = blockIdx.y;
  const int seg = threadIdx.x & (SPLIT - 1);
  const int al  = threadIdx.x >> 2;          // anchor-local 0..63
  const int i   = blockIdx.x * 64 + al;
  const int ic  = (i < A) ? i : (A - 1);

  const int len  = (G + SPLIT - 1) / SPLIT;
  const int padG = len * SPLIT;              // <= G_MAX

  if (threadIdx.x == 0) sNum = 0;

  // stage GT boxes (pad range with inert dummies: area=1e30)
  const float* gtb = boxes + (size_t)img * G * 5;
  for (int g = threadIdx.x; g < padG; g += 256) {
    if (g < G) {
      float x0 = gtb[g * 5 + 0], y0 = gtb[g * 5 + 1];
      float x1 = gtb[g * 5 + 2], y1 = gtb[g * 5 + 3];
      float lb = gtb[g * 5 + 4];
      sBox[g] = make_float4(x0, y0, x1 + 1.0f, y1 + 1.0f);
      sA[g] = (lb != -1.0f) ? (x1 - x0 + 1.0f) * (y1 - y0 + 1.0f) : 1e30f;
    } else {
      sBox[g] = make_float4(0.f, 0.f, 1.f, 1.f);
      sA[g] = 1e30f;
    }
  }
  __syncthreads();

  float t_cls = 0.f, t_bbox = 0.f, t_iou = 0.f, t_num = 0.f;
  float t_npos = 0.f, t_nfg = 0.f, t_ncnt = 0.f;

  const float BBOX_CLIP = 4.1351666f;  // log(1000/16)

  // per-anchor data (4 lanes share one anchor; redundant loads hit L1)
  float ax0 = anchors[ic * 4 + 0], ay0 = anchors[ic * 4 + 1];
  float ax1 = anchors[ic * 4 + 2], ay1 = anchors[ic * 4 + 3];
  float aw = ax1 - ax0 + 1.0f, ah = ay1 - ay0 + 1.0f;
  float areaa = aw * ah;
  float acx = ax0 + 0.5f * aw, acy = ay0 + 0.5f * ah;
  float ax1p = ax1 + 1.0f, ay1p = ay1 + 1.0f;

  // epilogue-only inputs: issue early (exec-masked to seg 0) to hide latency.
  // pred_reg deltas are only needed by seg 0 now (decode moved to needy path).
  float d0 = 0.f, d1 = 0.f, d2 = 0.f, d3 = 0.f;
  float d4 = 0.f, d5 = 0.f, d6 = 0.f, d7 = 0.f;
  float pcv0 = 0.f, pcv1 = 0.f, riv0 = 0.f, riv1 = 0.f, sn0 = 0.f, sn1 = 0.f;
  if (seg == 0) {
    const float* dp = pred_reg + ((size_t)img * A + ic) * 8;
    d0 = dp[0]; d1 = dp[1]; d2 = dp[2]; d3 = dp[3];
    d4 = dp[4]; d5 = dp[5]; d6 = dp[6]; d7 = dp[7];
    const float* pc = pred_cls + ((size_t)img * A + ic) * 2;
    pcv0 = pc[0]; pcv1 = pc[1];
    const float* ri = rpn_iou + ((size_t)img * A + ic) * 2;
    riv0 = ri[0]; riv1 = ri[1];
    const float* sp = rpn_num + ((size_t)img * A + ic) * 2;
    sn0 = sp[0]; sn1 = sp[1];
  }

  // ---------------- phase 1: anchor-vs-gt top-2 only ----------------
  // (decoded-box argmaxes deferred: only fg anchors ever consume aval/bval)
  uint32_t an1 = 0xFFFFFFFFu, an2 = 0xFFFFFFFFu;

  int g = seg * len;
#pragma unroll 15
  for (int t = 0; t < len; ++t, ++g) {
    float4 gb = sBox[g];
    float ga = sA[g];
    uint32_t p = packKey(ax0, ay0, ax1p, ay1p, areaa, gb, ga, (uint32_t)g);
    uint32_t hi = max(p, an1);
    an1 = min(an1, p);
    an2 = min(an2, hi);
  }

  // butterfly merge across the 4 lanes of this anchor
#pragma unroll
  for (int m = 1; m <= 2; m <<= 1) {
    uint32_t o1 = (uint32_t)__shfl_xor((int)an1, m, 64);
    uint32_t o2 = (uint32_t)__shfl_xor((int)an2, m, 64);
    uint32_t hi = max(an1, o1);
    an1 = min(an1, o1);
    an2 = min(min(an2, o2), hi);
  }

  bool fg0 = false, fg1 = false, needy = false;

  if (seg == 0 && i < A) {
    // winning indices; clamp defensively to the initialized LDS range
    int pg1 = padG - 1;
    int i0 = min((int)(an1 & 0x1FFu), pg1);
    int i1 = min((int)(an2 & 0x1FFu), pg1);

    // exact recompute of winning values (reference op order, explicit validity)
    float4 g0 = sBox[i0]; float a0 = sA[i0]; bool val0 = a0 < 1e29f;
    float v0 = val0 ? iouExact(ax0, ay0, ax1, ay1, areaa, g0, a0) : -1.0f;
    float4 g1 = sBox[i1]; float a1 = sA[i1]; bool val1 = a1 < 1e29f;
    float v1 = val1 ? iouExact(ax0, ay0, ax1, ay1, areaa, g1, a1) : -1.0f;

    // labels: >=0.5 -> 1, <0.4 -> 0, else -1
    float la  = (v0 >= 0.5f) ? 1.0f : ((v0 < 0.4f) ? 0.0f : -1.0f);
    float lbv = (v1 >= 0.5f) ? 1.0f : ((v1 < 0.4f) ? 0.0f : -1.0f);
    float lab0 = la;
    float lab1 = lbv - (((la == 0.0f) && (lbv != 0.0f)) ? 1.0f : 0.0f);

    // ---- focal classification loss ----
    {
      float p = pcv0;
      if (lab0 != -1.0f) {
        float l = (lab0 == 1.0f)
                      ? 0.25f * (1.0f - p) * (1.0f - p) * logf(p)
                      : 0.75f * p * p * logf(1.0f - p);
        t_cls -= l;
      }
      if (lab0 > 0.f) t_npos += 1.f;
      float q = pcv1;
      if (lab1 != -1.0f) {
        float l = (lab1 == 1.0f)
                      ? 0.25f * (1.0f - q) * (1.0f - q) * logf(q)
                      : 0.75f * q * q * logf(1.0f - q);
        t_cls -= l;
      }
      if (lab1 > 0.f) t_npos += 1.f;
    }

    fg0 = (lab0 != 0.0f) && (lab0 != -1.0f);
    fg1 = (lab1 != 0.0f) && (lab1 != -1.0f);

    // fast reciprocals for the bbox-target divides (rel err ~1e-7, harmless)
    float raw = __builtin_amdgcn_rcpf(aw), rah = __builtin_amdgcn_rcpf(ah);

    // ---- bbox smooth-L1 vs bbox_transform(anchor, matched gt) ----
    if (fg0) {
      float mx1 = g0.z - 1.0f, my1 = g0.w - 1.0f;
      float gw = mx1 - g0.x + 1.0f, gh = my1 - g0.y + 1.0f;
      float gcx = g0.x + 0.5f * gw, gcy = g0.y + 0.5f * gh;
      float t0 = (gcx - acx) * raw, t1v = (gcy - acy) * rah;
      float t2 = logf(gw * raw), t3 = logf(gh * rah);
      t_bbox += huber9(d0 - t0) + huber9(d1 - t1v) + huber9(d2 - t2) + huber9(d3 - t3);
      t_nfg += 1.f;
    }
    if (fg1) {
      float mx1 = g1.z - 1.0f, my1 = g1.w - 1.0f;
      float gw = mx1 - g1.x + 1.0f, gh = my1 - g1.y + 1.0f;
      float gcx = g1.x + 0.5f * gw, gcy = g1.y + 0.5f * gh;
      float t0 = (gcx - acx) * raw, t1v = (gcy - acy) * rah;
      float t2 = logf(gw * raw), t3 = logf(gh * rah);
      t_bbox += huber9(d4 - t0) + huber9(d5 - t1v) + huber9(d6 - t2) + huber9(d7 - t3);
      t_nfg += 1.f;
    }

    // ---- num softmax loss ----
    {
      int nl = ((lab0 > 0.f) ? 1 : 0) + ((lab1 > 0.f) ? 1 : 0) - 1;
      if (nl != -1) {
        float m = fmaxf(sn0, sn1);
        float lse = m + logf(expf(sn0 - m) + expf(sn1 - m));
        float picked = ((nl == 0) ? sn0 : sn1) - lse;
        t_num -= picked;
        t_ncnt += 1.f;
      }
    }

    // ---- enqueue for phase 2 (decoded-box argmaxes) only if fg ----
    needy = fg0 || fg1;
    if (needy) {
      // decode predicted boxes (identical expressions to the original prologue)
      float p0cx = acx + d0 * aw, p0cy = acy + d1 * ah;
      float p0w = aw * expf(fminf(d2, BBOX_CLIP));
      float p0h = ah * expf(fminf(d3, BBOX_CLIP));
      float b0x0 = p0cx - 0.5f * p0w, b0y0 = p0cy - 0.5f * p0h;
      float b0x1 = p0cx + 0.5f * p0w, b0y1 = p0cy + 0.5f * p0h;
      float area0 = (b0x1 - b0x0 + 1.0f) * (b0y1 - b0y0 + 1.0f);

      float p1cx = acx + d4 * aw, p1cy = acy + d5 * ah;
      float p1w = aw * expf(fminf(d6, BBOX_CLIP));
      float p1h = ah * expf(fminf(d7, BBOX_CLIP));
      float b1x0 = p1cx - 0.5f * p1w, b1y0 = p1cy - 0.5f * p1h;
      float b1x1 = p1cx + 0.5f * p1w, b1y1 = p1cy + 0.5f * p1h;
      float area1 = (b1x1 - b1x0 + 1.0f) * (b1y1 - b1y0 + 1.0f);

      int slot = atomicAdd(&sNum, 1);
      sList[slot] = (unsigned char)al;
      float* st = sStash[slot];
      st[0] = b0x0; st[1] = b0y0; st[2] = b0x1; st[3] = b0y1; st[4] = area0;
      st[5] = b1x0; st[6] = b1y0; st[7] = b1x1; st[8] = b1y1; st[9] = area1;
    }
  }
  __syncthreads();

  // ---------------- phase 2: compacted decoded-box argmaxes ----------------
  {
    int num = sNum;
    int slot = threadIdx.x >> 2;
    int wseg = threadIdx.x & 3;
    if (slot < num) {   // uniform across each quad -> shfl butterfly safe
      const float* st = sStash[slot];
      float c0x0 = st[0], c0y0 = st[1], c0x1 = st[2], c0y1 = st[3], car0 = st[4];
      float c1x0 = st[5], c1y0 = st[6], c1x1 = st[7], c1y1 = st[8], car1 = st[9];
      float c0x1p = c0x1 + 1.0f, c0y1p = c0y1 + 1.0f;
      float c1x1p = c1x1 + 1.0f, c1y1p = c1y1 + 1.0f;

      uint32_t am = 0xFFFFFFFFu;                    // box 0 best
      uint32_t bk1 = 0xFFFFFFFFu, bk2 = 0xFFFFFFFFu; // box 1 best/2nd

      int g2 = wseg * len;
#pragma unroll 15
      for (int t = 0; t < len; ++t, ++g2) {
        float4 gb = sBox[g2];
        float ga = sA[g2];
        am = min(am, packKey(c0x0, c0y0, c0x1p, c0y1p, car0, gb, ga, (uint32_t)g2));
        uint32_t p = packKey(c1x0, c1y0, c1x1p, c1y1p, car1, gb, ga, (uint32_t)g2);
        uint32_t hib = max(p, bk1);
        bk1 = min(bk1, p);
        bk2 = min(bk2, hib);
      }

#pragma unroll
      for (int m = 1; m <= 2; m <<= 1) {
        am = min(am, (uint32_t)__shfl_xor((int)am, m, 64));
        uint32_t q1 = (uint32_t)__shfl_xor((int)bk1, m, 64);
        uint32_t q2 = (uint32_t)__shfl_xor((int)bk2, m, 64);
        uint32_t hib = max(bk1, q1);
        bk1 = min(bk1, q1);
        bk2 = min(min(bk2, q2), hib);
      }

      if (wseg == 0) {
        int pg1 = padG - 1;
        int ai  = min((int)(am  & 0x1FFu), pg1);
        int bi  = min((int)(bk1 & 0x1FFu), pg1);
        int bi2 = min((int)(bk2 & 0x1FFu), pg1);
        float4 ga4 = sBox[ai]; float aav = sA[ai];
        float aval = (aav < 1e29f) ? iouExact(c0x0, c0y0, c0x1, c0y1, car0, ga4, aav) : 0.0f;
        int bIdx = (ai == bi) ? bi2 : bi;  // b with b[ai] zeroed, then argmax
        float4 gb4 = sBox[bIdx]; float abv = sA[bIdx];
        float bval = (abv < 1e29f) ? iouExact(c1x0, c1y0, c1x1, c1y1, car1, gb4, abv) : 0.0f;
        sRes[sList[slot]] = make_float2(aval, bval);
      }
    }
  }
  __syncthreads();

  // ---- IoU L1 loss (owner lane reads phase-2 result) ----
  if (needy) {   // implies seg==0 && i<A
    float2 r = sRes[al];
    if (fg0) t_iou += fabsf(riv0 - r.x);
    if (fg1) t_iou += fabsf(riv1 - fmaxf(r.y, 0.0f));
  }

  // block reduction: wave shuffle -> LDS -> one double atomic per scalar
  float vals[7] = {t_cls, t_bbox, t_iou, t_num, t_npos, t_nfg, t_ncnt};
  int lane = threadIdx.x & 63;
  int wid = threadIdx.x >> 6;
#pragma unroll
  for (int k = 0; k < 7; ++k) {
    float s = waveSum(vals[k]);
    if (lane == 0) sRed[wid][k] = s;
  }
  __syncthreads();
  if (threadIdx.x < 7) {
    double s = (double)sRed[0][threadIdx.x] + (double)sRed[1][threadIdx.x] +
               (double)sRed[2][threadIdx.x] + (double)sRed[3][threadIdx.x];
    atomicAdd(&acc[threadIdx.x * 16], s);  // 128 B apart, device-scope
    __threadfence();                       // release our adds device-wide
  }
  __syncthreads();
  if (threadIdx.x == 0) {
    unsigned int old = atomicAdd(cnt, 1u); // ticket; device-scope
    sLast = (old == (unsigned int)(totalBlocks - 1)) ? 1 : 0;
  }
  __syncthreads();

  // last block finalizes: read accumulators through the atomic domain
  if (sLast && threadIdx.x == 0) {
    __threadfence();
    double cls  = atomicAdd(&acc[0 * 16], 0.0);
    double bbox = atomicAdd(&acc[1 * 16], 0.0);
    double iou  = atomicAdd(&acc[2 * 16], 0.0);
    double num  = atomicAdd(&acc[3 * 16], 0.0);
    double npos = atomicAdd(&acc[4 * 16], 0.0);
    double nfg  = atomicAdd(&acc[5 * 16], 0.0);
    double ncnt = atomicAdd(&acc[6 * 16], 0.0);
    double dpos = npos > 1.0 ? npos : 1.0;
    double dfg  = nfg  > 1.0 ? nfg  : 1.0;
    double dcnt = ncnt > 1.0 ? ncnt : 1.0;
    out[0] = (float)(cls / dpos);
    out[1] = (float)(2.0 * bbox / dfg);
    out[2] = (float)(2.0 * iou / dfg);
    out[3] = (float)(num / dcnt);
  }
}

extern "C" void kernel_launch(void* const* d_in, const int* in_sizes, int n_in,
                              void* d_out, int out_size, void* d_ws, size_t ws_size,
                              hipStream_t stream) {
  const float* pred_cls = (const float*)d_in[0];
  const float* rpn_num  = (const float*)d_in[1];
  const float* pred_reg = (const float*)d_in[2];
  const float* anchors  = (const float*)d_in[3];
  const float* rpn_iou  = (const float*)d_in[4];
  const float* boxes    = (const float*)d_in[5];
  // d_in[6] = im_info: unused by the reference math

  int A = in_sizes[3] / 4;
  int n = in_sizes[0] / (2 * A);
  int G = in_sizes[5] / (5 * n);

  double* acc = (double*)d_ws;                       // 7 x stride-16 doubles
  unsigned int* cnt = (unsigned int*)((char*)d_ws + 7 * 16 * sizeof(double));
  hipMemsetAsync(d_ws, 0, 7 * 16 * sizeof(double) + sizeof(unsigned int), stream);

  int nBx = (A + 63) / 64;
  int totalBlocks = nBx * n;
  dim3 grid(nBx, n, 1);  // 64 anchors/block x SPLIT=4 lanes
  retina_main<<<grid, dim3(256, 1, 1), 0, stream>>>(
      pred_cls, rpn_num, pred_reg, anchors, rpn_iou, boxes,
      A, G, totalBlocks, acc, cnt, (float*)d_out);
}

// Round 2
// 154.682 us; speedup vs baseline: 1.1507x; 1.1416x over previous
//
#include <hip/hip_runtime.h>
#include <math.h>

#define G_MAX 512   // LDS capacity for GT boxes; setup uses G=300
#define SPLIT 4     // threads per anchor (g-loop split)

__device__ __forceinline__ float waveSum(float v) {
#pragma unroll
  for (int o = 32; o > 0; o >>= 1) v += __shfl_down(v, o, 64);
  return v;
}

// smooth-L1 with sigma=3 (s2=9)
__device__ __forceinline__ float huber9(float x) {
  float ax = fabsf(x);
  return (ax < (1.0f / 9.0f)) ? 4.5f * x * x : ax - (0.5f / 9.0f);
}

// Exact IoU in the reference's op order. g = (x0, y0, x1+1, y1+1)
__device__ __forceinline__ float iouExact(float bx0, float by0, float bx1, float by1,
                                          float areab, float4 g, float areag) {
  float gx1 = g.z - 1.0f, gy1 = g.w - 1.0f;  // exact inverse of the staged +1
  float iw = fminf(bx1, gx1) - fmaxf(bx0, g.x) + 1.0f;
  float ih = fminf(by1, gy1) - fmaxf(by0, g.y) + 1.0f;
  float inter = fmaxf(iw, 0.f) * fmaxf(ih, 0.f);
  float uni = areab + areag - inter;
  return inter / fmaxf(uni, 1.0f);
}

// Inverse comparison key: key = (areaB+areaG)*rcp(inter); argmax iou == argmin
// key (uint compare on positive floats). ONE-CLAMP trick: inter = max(iw,0)*ih.
//   ih >= 0: identical to the two-clamp value (positive-overlap keys exact).
//   ih <  0: inter <= -0 -> key negative or -inf -> uint >= 0x80000000 ->
//            ranks below ALL positive keys under min-tracking, i.e. in the
//            zero-overlap class, whose internal order is output-invariant
//            (winners are recomputed exactly with validity masks; all
//            zero-overlap/invalid picks yield label 0 / fg=false / value 0).
// Low 9 bits carry g: min-ties resolve to smallest g (jax stable semantics).
// Never NaN: S>0 finite, S*(+-inf)=+-inf.
__device__ __forceinline__ uint32_t packKey(float x0, float y0, float x1p, float y1p,
                                            float area, float4 gb, float ga,
                                            uint32_t g) {
  float iw = fminf(x1p, gb.z) - fmaxf(x0, gb.x);
  float ih = fminf(y1p, gb.w) - fmaxf(y0, gb.y);
  float inter = fmaxf(iw, 0.f) * ih;
  float key = (area + ga) * __builtin_amdgcn_rcpf(inter);
  return (__float_as_uint(key) & 0xFFFFFE00u) | g;
}

__global__ __launch_bounds__(256) void retina_main(
    const float* __restrict__ pred_cls,   // (n, A, 2)
    const float* __restrict__ rpn_num,    // (n, A, 2)
    const float* __restrict__ pred_reg,   // (n, A, 8)
    const float* __restrict__ anchors,    // (A, 4)
    const float* __restrict__ rpn_iou,    // (n, A, 2)
    const float* __restrict__ boxes,      // (n, G, 5)
    int A, int G,
    double* __restrict__ partial)         // (nB, 8) doubles, private per block
{
  __shared__ float4 sBox[G_MAX];  // x0, y0, x1+1, y1+1
  __shared__ float sA[G_MAX];     // area (1e30 for invalid/dummy)
  __shared__ float sRed[4][7];
  __shared__ float sStash[64][10];      // decoded boxes of needy anchors (by slot)
  __shared__ float2 sRes[64];           // aval/bval results (by anchor-local al)
  __shared__ unsigned char sList[64];   // slot -> al
  __shared__ int sNum;

  const int img = blockIdx.y;
  const int seg = threadIdx.x & (SPLIT - 1);
  const int al  = threadIdx.x >> 2;          // anchor-local 0..63
  const int i   = blockIdx.x * 64 + al;
  const int ic  = (i < A) ? i : (A - 1);

  const int len  = (G + SPLIT - 1) / SPLIT;
  const int padG = len * SPLIT;              // <= G_MAX

  if (threadIdx.x == 0) sNum = 0;

  // stage GT boxes (pad range with inert dummies: area=1e30)
  const float* gtb = boxes + (size_t)img * G * 5;
  for (int g = threadIdx.x; g < padG; g += 256) {
    if (g < G) {
      float x0 = gtb[g * 5 + 0], y0 = gtb[g * 5 + 1];
      float x1 = gtb[g * 5 + 2], y1 = gtb[g * 5 + 3];
      float lb = gtb[g * 5 + 4];
      sBox[g] = make_float4(x0, y0, x1 + 1.0f, y1 + 1.0f);
      sA[g] = (lb != -1.0f) ? (x1 - x0 + 1.0f) * (y1 - y0 + 1.0f) : 1e30f;
    } else {
      sBox[g] = make_float4(0.f, 0.f, 1.f, 1.f);
      sA[g] = 1e30f;
    }
  }
  __syncthreads();

  float t_cls = 0.f, t_bbox = 0.f, t_iou = 0.f, t_num = 0.f;
  float t_npos = 0.f, t_nfg = 0.f, t_ncnt = 0.f;

  const float BBOX_CLIP = 4.1351666f;  // log(1000/16)

  // per-anchor data (4 lanes share one anchor; redundant loads hit L1)
  float ax0 = anchors[ic * 4 + 0], ay0 = anchors[ic * 4 + 1];
  float ax1 = anchors[ic * 4 + 2], ay1 = anchors[ic * 4 + 3];
  float aw = ax1 - ax0 + 1.0f, ah = ay1 - ay0 + 1.0f;
  float areaa = aw * ah;
  float acx = ax0 + 0.5f * aw, acy = ay0 + 0.5f * ah;
  float ax1p = ax1 + 1.0f, ay1p = ay1 + 1.0f;

  // epilogue-only inputs: issue early (exec-masked to seg 0) to hide latency.
  // pred_reg deltas are only needed by seg 0 now (decode moved to needy path).
  float d0 = 0.f, d1 = 0.f, d2 = 0.f, d3 = 0.f;
  float d4 = 0.f, d5 = 0.f, d6 = 0.f, d7 = 0.f;
  float pcv0 = 0.f, pcv1 = 0.f, riv0 = 0.f, riv1 = 0.f, sn0 = 0.f, sn1 = 0.f;
  if (seg == 0) {
    const float* dp = pred_reg + ((size_t)img * A + ic) * 8;
    d0 = dp[0]; d1 = dp[1]; d2 = dp[2]; d3 = dp[3];
    d4 = dp[4]; d5 = dp[5]; d6 = dp[6]; d7 = dp[7];
    const float* pc = pred_cls + ((size_t)img * A + ic) * 2;
    pcv0 = pc[0]; pcv1 = pc[1];
    const float* ri = rpn_iou + ((size_t)img * A + ic) * 2;
    riv0 = ri[0]; riv1 = ri[1];
    const float* sp = rpn_num + ((size_t)img * A + ic) * 2;
    sn0 = sp[0]; sn1 = sp[1];
  }

  // ---------------- phase 1: anchor-vs-gt top-2 only ----------------
  // (decoded-box argmaxes deferred: only fg anchors ever consume aval/bval)
  uint32_t an1 = 0xFFFFFFFFu, an2 = 0xFFFFFFFFu;

  int g = seg * len;
#pragma unroll 15
  for (int t = 0; t < len; ++t, ++g) {
    float4 gb = sBox[g];
    float ga = sA[g];
    uint32_t p = packKey(ax0, ay0, ax1p, ay1p, areaa, gb, ga, (uint32_t)g);
    uint32_t hi = max(p, an1);
    an1 = min(an1, p);
    an2 = min(an2, hi);
  }

  // butterfly merge across the 4 lanes of this anchor
#pragma unroll
  for (int m = 1; m <= 2; m <<= 1) {
    uint32_t o1 = (uint32_t)__shfl_xor((int)an1, m, 64);
    uint32_t o2 = (uint32_t)__shfl_xor((int)an2, m, 64);
    uint32_t hi = max(an1, o1);
    an1 = min(an1, o1);
    an2 = min(min(an2, o2), hi);
  }

  bool fg0 = false, fg1 = false, needy = false;

  if (seg == 0 && i < A) {
    // winning indices; clamp defensively to the initialized LDS range
    int pg1 = padG - 1;
    int i0 = min((int)(an1 & 0x1FFu), pg1);
    int i1 = min((int)(an2 & 0x1FFu), pg1);

    // exact recompute of winning values (reference op order, explicit validity)
    float4 g0 = sBox[i0]; float a0 = sA[i0]; bool val0 = a0 < 1e29f;
    float v0 = val0 ? iouExact(ax0, ay0, ax1, ay1, areaa, g0, a0) : -1.0f;
    float4 g1 = sBox[i1]; float a1 = sA[i1]; bool val1 = a1 < 1e29f;
    float v1 = val1 ? iouExact(ax0, ay0, ax1, ay1, areaa, g1, a1) : -1.0f;

    // labels: >=0.5 -> 1, <0.4 -> 0, else -1
    float la  = (v0 >= 0.5f) ? 1.0f : ((v0 < 0.4f) ? 0.0f : -1.0f);
    float lbv = (v1 >= 0.5f) ? 1.0f : ((v1 < 0.4f) ? 0.0f : -1.0f);
    float lab0 = la;
    float lab1 = lbv - (((la == 0.0f) && (lbv != 0.0f)) ? 1.0f : 0.0f);

    // ---- focal classification loss ----
    {
      float p = pcv0;
      if (lab0 != -1.0f) {
        float l = (lab0 == 1.0f)
                      ? 0.25f * (1.0f - p) * (1.0f - p) * logf(p)
                      : 0.75f * p * p * logf(1.0f - p);
        t_cls -= l;
      }
      if (lab0 > 0.f) t_npos += 1.f;
      float q = pcv1;
      if (lab1 != -1.0f) {
        float l = (lab1 == 1.0f)
                      ? 0.25f * (1.0f - q) * (1.0f - q) * logf(q)
                      : 0.75f * q * q * logf(1.0f - q);
        t_cls -= l;
      }
      if (lab1 > 0.f) t_npos += 1.f;
    }

    fg0 = (lab0 != 0.0f) && (lab0 != -1.0f);
    fg1 = (lab1 != 0.0f) && (lab1 != -1.0f);

    // fast reciprocals for the bbox-target divides (rel err ~1e-7, harmless)
    float raw = __builtin_amdgcn_rcpf(aw), rah = __builtin_amdgcn_rcpf(ah);

    // ---- bbox smooth-L1 vs bbox_transform(anchor, matched gt) ----
    if (fg0) {
      float mx1 = g0.z - 1.0f, my1 = g0.w - 1.0f;
      float gw = mx1 - g0.x + 1.0f, gh = my1 - g0.y + 1.0f;
      float gcx = g0.x + 0.5f * gw, gcy = g0.y + 0.5f * gh;
      float t0 = (gcx - acx) * raw, t1v = (gcy - acy) * rah;
      float t2 = logf(gw * raw), t3 = logf(gh * rah);
      t_bbox += huber9(d0 - t0) + huber9(d1 - t1v) + huber9(d2 - t2) + huber9(d3 - t3);
      t_nfg += 1.f;
    }
    if (fg1) {
      float mx1 = g1.z - 1.0f, my1 = g1.w - 1.0f;
      float gw = mx1 - g1.x + 1.0f, gh = my1 - g1.y + 1.0f;
      float gcx = g1.x + 0.5f * gw, gcy = g1.y + 0.5f * gh;
      float t0 = (gcx - acx) * raw, t1v = (gcy - acy) * rah;
      float t2 = logf(gw * raw), t3 = logf(gh * rah);
      t_bbox += huber9(d4 - t0) + huber9(d5 - t1v) + huber9(d6 - t2) + huber9(d7 - t3);
      t_nfg += 1.f;
    }

    // ---- num softmax loss ----
    {
      int nl = ((lab0 > 0.f) ? 1 : 0) + ((lab1 > 0.f) ? 1 : 0) - 1;
      if (nl != -1) {
        float m = fmaxf(sn0, sn1);
        float lse = m + logf(expf(sn0 - m) + expf(sn1 - m));
        float picked = ((nl == 0) ? sn0 : sn1) - lse;
        t_num -= picked;
        t_ncnt += 1.f;
      }
    }

    // ---- enqueue for phase 2 (decoded-box argmaxes) only if fg ----
    needy = fg0 || fg1;
    if (needy) {
      // decode predicted boxes (identical expressions to the original prologue)
      float p0cx = acx + d0 * aw, p0cy = acy + d1 * ah;
      float p0w = aw * expf(fminf(d2, BBOX_CLIP));
      float p0h = ah * expf(fminf(d3, BBOX_CLIP));
      float b0x0 = p0cx - 0.5f * p0w, b0y0 = p0cy - 0.5f * p0h;
      float b0x1 = p0cx + 0.5f * p0w, b0y1 = p0cy + 0.5f * p0h;
      float area0 = (b0x1 - b0x0 + 1.0f) * (b0y1 - b0y0 + 1.0f);

      float p1cx = acx + d4 * aw, p1cy = acy + d5 * ah;
      float p1w = aw * expf(fminf(d6, BBOX_CLIP));
      float p1h = ah * expf(fminf(d7, BBOX_CLIP));
      float b1x0 = p1cx - 0.5f * p1w, b1y0 = p1cy - 0.5f * p1h;
      float b1x1 = p1cx + 0.5f * p1w, b1y1 = p1cy + 0.5f * p1h;
      float area1 = (b1x1 - b1x0 + 1.0f) * (b1y1 - b1y0 + 1.0f);

      int slot = atomicAdd(&sNum, 1);
      sList[slot] = (unsigned char)al;
      float* st = sStash[slot];
      st[0] = b0x0; st[1] = b0y0; st[2] = b0x1; st[3] = b0y1; st[4] = area0;
      st[5] = b1x0; st[6] = b1y0; st[7] = b1x1; st[8] = b1y1; st[9] = area1;
    }
  }
  __syncthreads();

  // ---------------- phase 2: compacted decoded-box argmaxes ----------------
  {
    int num = sNum;
    int slot = threadIdx.x >> 2;
    int wseg = threadIdx.x & 3;
    if (slot < num) {   // uniform across each quad -> shfl butterfly safe
      const float* st = sStash[slot];
      float c0x0 = st[0], c0y0 = st[1], c0x1 = st[2], c0y1 = st[3], car0 = st[4];
      float c1x0 = st[5], c1y0 = st[6], c1x1 = st[7], c1y1 = st[8], car1 = st[9];
      float c0x1p = c0x1 + 1.0f, c0y1p = c0y1 + 1.0f;
      float c1x1p = c1x1 + 1.0f, c1y1p = c1y1 + 1.0f;

      uint32_t am = 0xFFFFFFFFu;                    // box 0 best
      uint32_t bk1 = 0xFFFFFFFFu, bk2 = 0xFFFFFFFFu; // box 1 best/2nd

      int g2 = wseg * len;
#pragma unroll 15
      for (int t = 0; t < len; ++t, ++g2) {
        float4 gb = sBox[g2];
        float ga = sA[g2];
        am = min(am, packKey(c0x0, c0y0, c0x1p, c0y1p, car0, gb, ga, (uint32_t)g2));
        uint32_t p = packKey(c1x0, c1y0, c1x1p, c1y1p, car1, gb, ga, (uint32_t)g2);
        uint32_t hib = max(p, bk1);
        bk1 = min(bk1, p);
        bk2 = min(bk2, hib);
      }

#pragma unroll
      for (int m = 1; m <= 2; m <<= 1) {
        am = min(am, (uint32_t)__shfl_xor((int)am, m, 64));
        uint32_t q1 = (uint32_t)__shfl_xor((int)bk1, m, 64);
        uint32_t q2 = (uint32_t)__shfl_xor((int)bk2, m, 64);
        uint32_t hib = max(bk1, q1);
        bk1 = min(bk1, q1);
        bk2 = min(min(bk2, q2), hib);
      }

      if (wseg == 0) {
        int pg1 = padG - 1;
        int ai  = min((int)(am  & 0x1FFu), pg1);
        int bi  = min((int)(bk1 & 0x1FFu), pg1);
        int bi2 = min((int)(bk2 & 0x1FFu), pg1);
        float4 ga4 = sBox[ai]; float aav = sA[ai];
        float aval = (aav < 1e29f) ? iouExact(c0x0, c0y0, c0x1, c0y1, car0, ga4, aav) : 0.0f;
        int bIdx = (ai == bi) ? bi2 : bi;  // b with b[ai] zeroed, then argmax
        float4 gb4 = sBox[bIdx]; float abv = sA[bIdx];
        float bval = (abv < 1e29f) ? iouExact(c1x0, c1y0, c1x1, c1y1, car1, gb4, abv) : 0.0f;
        sRes[sList[slot]] = make_float2(aval, bval);
      }
    }
  }
  __syncthreads();

  // ---- IoU L1 loss (owner lane reads phase-2 result) ----
  if (needy) {   // implies seg==0 && i<A
    float2 r = sRes[al];
    if (fg0) t_iou += fabsf(riv0 - r.x);
    if (fg1) t_iou += fabsf(riv1 - fmaxf(r.y, 0.0f));
  }

  // block reduction: wave shuffle -> LDS -> one private record per block.
  // NO global atomics: 3750 blocks x 7 same-line device-scope atomicAdds
  // serialized at the coherence point and pinned the kernel at ~114 us.
  float vals[7] = {t_cls, t_bbox, t_iou, t_num, t_npos, t_nfg, t_ncnt};
  int lane = threadIdx.x & 63;
  int wid = threadIdx.x >> 6;
#pragma unroll
  for (int k = 0; k < 7; ++k) {
    float s = waveSum(vals[k]);
    if (lane == 0) sRed[wid][k] = s;
  }
  __syncthreads();
  if (threadIdx.x < 7) {
    double s = (double)sRed[0][threadIdx.x] + (double)sRed[1][threadIdx.x] +
               (double)sRed[2][threadIdx.x] + (double)sRed[3][threadIdx.x];
    size_t bid = (size_t)blockIdx.y * gridDim.x + blockIdx.x;
    partial[bid * 8 + threadIdx.x] = s;    // 64-B record, no contention
  }
}

// Second dispatch on the same stream: kernel-boundary ordering makes the
// partial records visible. Sums 3750 x 7 doubles (240 KB, L2/LLC-resident).
__global__ __launch_bounds__(256) void retina_finalize(
    const double* __restrict__ partial, int nB, float* __restrict__ out) {
  __shared__ double sRed[4][7];
  double loc[7] = {0.0, 0.0, 0.0, 0.0, 0.0, 0.0, 0.0};
  for (int b = threadIdx.x; b < nB; b += 256) {
    const double* r = partial + (size_t)b * 8;
#pragma unroll
    for (int k = 0; k < 7; ++k) loc[k] += r[k];
  }
  int lane = threadIdx.x & 63;
  int wid = threadIdx.x >> 6;
#pragma unroll
  for (int k = 0; k < 7; ++k) {
    double v = loc[k];
#pragma unroll
    for (int o = 32; o > 0; o >>= 1) v += __shfl_down(v, o, 64);
    if (lane == 0) sRed[wid][k] = v;
  }
  __syncthreads();
  if (threadIdx.x == 0) {
    double t[7];
#pragma unroll
    for (int k = 0; k < 7; ++k)
      t[k] = sRed[0][k] + sRed[1][k] + sRed[2][k] + sRed[3][k];
    double dpos = t[4] > 1.0 ? t[4] : 1.0;
    double dfg  = t[5] > 1.0 ? t[5] : 1.0;
    double dcnt = t[6] > 1.0 ? t[6] : 1.0;
    out[0] = (float)(t[0] / dpos);
    out[1] = (float)(2.0 * t[1] / dfg);
    out[2] = (float)(2.0 * t[2] / dfg);
    out[3] = (float)(t[3] / dcnt);
  }
}

extern "C" void kernel_launch(void* const* d_in, const int* in_sizes, int n_in,
                              void* d_out, int out_size, void* d_ws, size_t ws_size,
                              hipStream_t stream) {
  const float* pred_cls = (const float*)d_in[0];
  const float* rpn_num  = (const float*)d_in[1];
  const float* pred_reg = (const float*)d_in[2];
  const float* anchors  = (const float*)d_in[3];
  const float* rpn_iou  = (const float*)d_in[4];
  const float* boxes    = (const float*)d_in[5];
  // d_in[6] = im_info: unused by the reference math

  int A = in_sizes[3] / 4;
  int n = in_sizes[0] / (2 * A);
  int G = in_sizes[5] / (5 * n);

  double* partial = (double*)d_ws;  // (nB, 8) doubles = 64 B per block

  int nBx = (A + 63) / 64;
  int nB = nBx * n;
  dim3 grid(nBx, n, 1);  // 64 anchors/block x SPLIT=4 lanes
  retina_main<<<grid, dim3(256, 1, 1), 0, stream>>>(
      pred_cls, rpn_num, pred_reg, anchors, rpn_iou, boxes,
      A, G, partial);
  retina_finalize<<<dim3(1, 1, 1), dim3(256, 1, 1), 0, stream>>>(
      partial, nB, (float*)d_out);
}

// Round 3
// 149.198 us; speedup vs baseline: 1.1930x; 1.0368x over previous
//
#include <hip/hip_runtime.h>
#include <math.h>

#define G_MAX 512   // LDS capacity for GT boxes; setup uses G=300
#define SPLIT 4     // threads per anchor (g-loop split)
#define APQ 2       // anchors per quad: each gb/ga load feeds APQ packKeys

__device__ __forceinline__ float waveSum(float v) {
#pragma unroll
  for (int o = 32; o > 0; o >>= 1) v += __shfl_down(v, o, 64);
  return v;
}

// smooth-L1 with sigma=3 (s2=9)
__device__ __forceinline__ float huber9(float x) {
  float ax = fabsf(x);
  return (ax < (1.0f / 9.0f)) ? 4.5f * x * x : ax - (0.5f / 9.0f);
}

// Exact IoU in the reference's op order. g = (x0, y0, x1+1, y1+1)
__device__ __forceinline__ float iouExact(float bx0, float by0, float bx1, float by1,
                                          float areab, float4 g, float areag) {
  float gx1 = g.z - 1.0f, gy1 = g.w - 1.0f;  // exact inverse of the staged +1 (coords < 2^24)
  float iw = fminf(bx1, gx1) - fmaxf(bx0, g.x) + 1.0f;
  float ih = fminf(by1, gy1) - fmaxf(by0, g.y) + 1.0f;
  float inter = fmaxf(iw, 0.f) * fmaxf(ih, 0.f);
  float uni = areab + areag - inter;
  return inter / fmaxf(uni, 1.0f);
}

// Inverse comparison key: key = (areaB+areaG)*rcp(inter); argmax iou == argmin
// key (uint compare on positive floats). ONE-CLAMP trick: inter = max(iw,0)*ih.
//   ih >= 0: identical to the two-clamp value (positive-overlap keys exact).
//   ih <  0: inter <= -0 -> key negative or -inf -> uint >= 0x80000000 ->
//            ranks below ALL positive keys under min-tracking, i.e. in the
//            zero-overlap class, whose internal order is output-invariant
//            (winners are recomputed exactly with validity masks; all
//            zero-overlap/invalid picks yield label 0 / fg=false / value 0).
// Low 9 bits carry g: min-ties resolve to smallest g (jax stable semantics).
// Never NaN: S>0 finite, S*(+-inf)=+-inf.
__device__ __forceinline__ uint32_t packKey(float x0, float y0, float x1p, float y1p,
                                            float area, float4 gb, float ga,
                                            uint32_t g) {
  float iw = fminf(x1p, gb.z) - fmaxf(x0, gb.x);
  float ih = fminf(y1p, gb.w) - fmaxf(y0, gb.y);
  float inter = fmaxf(iw, 0.f) * ih;
  float key = (area + ga) * __builtin_amdgcn_rcpf(inter);
  return (__float_as_uint(key) & 0xFFFFFE00u) | g;
}

__global__ __launch_bounds__(256, 4) void retina_main(
    const float* __restrict__ pred_cls,   // (n, A, 2)
    const float* __restrict__ rpn_num,    // (n, A, 2)
    const float* __restrict__ pred_reg,   // (n, A, 8)
    const float* __restrict__ anchors,    // (A, 4)
    const float* __restrict__ rpn_iou,    // (n, A, 2)
    const float* __restrict__ boxes,      // (n, G, 5)
    int A, int G,
    double* __restrict__ partial)         // (nB, 8) doubles, private per block
{
  __shared__ float4 sBox[G_MAX];  // x0, y0, x1+1, y1+1
  __shared__ float sA[G_MAX];     // area (1e30 for invalid/dummy)
  __shared__ float sRed[4][7];
  __shared__ float sStash[128][10];     // decoded boxes of needy anchors (by slot)
  __shared__ float2 sRes[128];          // aval/bval results (by anchor-local id)
  __shared__ unsigned char sList[128];  // slot -> anchor-local id (q + 64*k)
  __shared__ int sNum;

  const int img = blockIdx.y;
  const int seg = threadIdx.x & (SPLIT - 1);
  const int q   = threadIdx.x >> 2;          // quad id 0..63
  const int base = blockIdx.x * (64 * APQ);

  int idx[APQ];
  idx[0] = base + q;
  idx[1] = base + 64 + q;

  const int len  = (G + SPLIT - 1) / SPLIT;
  const int padG = len * SPLIT;              // <= G_MAX

  if (threadIdx.x == 0) sNum = 0;

  // stage GT boxes (pad range with inert dummies: area=1e30)
  const float* gtb = boxes + (size_t)img * G * 5;
  for (int g = threadIdx.x; g < padG; g += 256) {
    if (g < G) {
      float x0 = gtb[g * 5 + 0], y0 = gtb[g * 5 + 1];
      float x1 = gtb[g * 5 + 2], y1 = gtb[g * 5 + 3];
      float lb = gtb[g * 5 + 4];
      sBox[g] = make_float4(x0, y0, x1 + 1.0f, y1 + 1.0f);
      sA[g] = (lb != -1.0f) ? (x1 - x0 + 1.0f) * (y1 - y0 + 1.0f) : 1e30f;
    } else {
      sBox[g] = make_float4(0.f, 0.f, 1.f, 1.f);
      sA[g] = 1e30f;
    }
  }
  __syncthreads();

  float t_cls = 0.f, t_bbox = 0.f, t_iou = 0.f, t_num = 0.f;
  float t_npos = 0.f, t_nfg = 0.f, t_ncnt = 0.f;

  const float BBOX_CLIP = 4.1351666f;  // log(1000/16)

  // Minimal per-anchor loop constants (5 regs/anchor). Everything else
  // (centers, widths, epilogue inputs) is (re)loaded lazily at the epilogue
  // so the hot loop keeps register pressure low and the compiler can
  // software-pipeline the LDS reads (unroll 5 below).
  float x0[APQ], y0[APQ], x1p[APQ], y1p[APQ], area[APQ];
#pragma unroll
  for (int k = 0; k < APQ; ++k) {
    int ic = (idx[k] < A) ? idx[k] : (A - 1);
    float ax0 = anchors[ic * 4 + 0], ay0 = anchors[ic * 4 + 1];
    float ax1 = anchors[ic * 4 + 2], ay1 = anchors[ic * 4 + 3];
    float aw = ax1 - ax0 + 1.0f, ah = ay1 - ay0 + 1.0f;
    x0[k] = ax0; y0[k] = ay0;
    x1p[k] = ax1 + 1.0f; y1p[k] = ay1 + 1.0f;
    area[k] = aw * ah;
  }

  // ---------------- phase 1: anchor-vs-gt top-2 (APQ anchors share each load) ----
  uint32_t an1[APQ] = {0xFFFFFFFFu, 0xFFFFFFFFu};
  uint32_t an2[APQ] = {0xFFFFFFFFu, 0xFFFFFFFFu};

  int g = seg * len;
#pragma unroll 5
  for (int t = 0; t < len; ++t, ++g) {
    float4 gb = sBox[g];
    float ga = sA[g];
#pragma unroll
    for (int k = 0; k < APQ; ++k) {
      uint32_t p = packKey(x0[k], y0[k], x1p[k], y1p[k], area[k], gb, ga, (uint32_t)g);
      uint32_t hi = max(p, an1[k]);
      an1[k] = min(an1[k], p);
      an2[k] = min(an2[k], hi);
    }
  }

  // butterfly merge across the 4 lanes of this quad
#pragma unroll
  for (int m = 1; m <= 2; m <<= 1) {
#pragma unroll
    for (int k = 0; k < APQ; ++k) {
      uint32_t o1 = (uint32_t)__shfl_xor((int)an1[k], m, 64);
      uint32_t o2 = (uint32_t)__shfl_xor((int)an2[k], m, 64);
      uint32_t hi = max(an1[k], o1);
      an1[k] = min(an1[k], o1);
      an2[k] = min(min(an2[k], o2), hi);
    }
  }

  bool fg0[APQ] = {false, false}, fg1[APQ] = {false, false};
  bool needy[APQ] = {false, false};
  float riv0[APQ], riv1[APQ];

  if (seg == 0) {
#pragma unroll
    for (int k = 0; k < APQ; ++k) {
      if (idx[k] >= A) continue;
      const int ic = idx[k];

      // lazy epilogue loads (once per block; latency amortized across waves)
      const float* dp = pred_reg + ((size_t)img * A + ic) * 8;
      float d0 = dp[0], d1 = dp[1], d2 = dp[2], d3 = dp[3];
      float d4 = dp[4], d5 = dp[5], d6 = dp[6], d7 = dp[7];
      const float* pc = pred_cls + ((size_t)img * A + ic) * 2;
      float pcv0 = pc[0], pcv1 = pc[1];
      const float* ri = rpn_iou + ((size_t)img * A + ic) * 2;
      riv0[k] = ri[0]; riv1[k] = ri[1];
      const float* sp = rpn_num + ((size_t)img * A + ic) * 2;
      float sn0 = sp[0], sn1 = sp[1];

      // recover full anchor geometry (exact: +1 is exact for |v| < 2^24)
      float ax0 = x0[k], ay0 = y0[k];
      float ax1 = x1p[k] - 1.0f, ay1 = y1p[k] - 1.0f;
      float aw = ax1 - ax0 + 1.0f, ah = ay1 - ay0 + 1.0f;
      float areaa = area[k];
      float acx = ax0 + 0.5f * aw, acy = ay0 + 0.5f * ah;

      // winning indices; clamp defensively to the initialized LDS range
      int pg1 = padG - 1;
      int i0 = min((int)(an1[k] & 0x1FFu), pg1);
      int i1 = min((int)(an2[k] & 0x1FFu), pg1);

      // exact recompute of winning values (reference op order, explicit validity)
      float4 g0 = sBox[i0]; float a0 = sA[i0]; bool val0 = a0 < 1e29f;
      float v0 = val0 ? iouExact(ax0, ay0, ax1, ay1, areaa, g0, a0) : -1.0f;
      float4 g1 = sBox[i1]; float a1 = sA[i1]; bool val1 = a1 < 1e29f;
      float v1 = val1 ? iouExact(ax0, ay0, ax1, ay1, areaa, g1, a1) : -1.0f;

      // labels: >=0.5 -> 1, <0.4 -> 0, else -1
      float la  = (v0 >= 0.5f) ? 1.0f : ((v0 < 0.4f) ? 0.0f : -1.0f);
      float lbv = (v1 >= 0.5f) ? 1.0f : ((v1 < 0.4f) ? 0.0f : -1.0f);
      float lab0 = la;
      float lab1 = lbv - (((la == 0.0f) && (lbv != 0.0f)) ? 1.0f : 0.0f);

      // ---- focal classification loss ----
      {
        float p = pcv0;
        if (lab0 != -1.0f) {
          float l = (lab0 == 1.0f)
                        ? 0.25f * (1.0f - p) * (1.0f - p) * logf(p)
                        : 0.75f * p * p * logf(1.0f - p);
          t_cls -= l;
        }
        if (lab0 > 0.f) t_npos += 1.f;
        float qv = pcv1;
        if (lab1 != -1.0f) {
          float l = (lab1 == 1.0f)
                        ? 0.25f * (1.0f - qv) * (1.0f - qv) * logf(qv)
                        : 0.75f * qv * qv * logf(1.0f - qv);
          t_cls -= l;
        }
        if (lab1 > 0.f) t_npos += 1.f;
      }

      fg0[k] = (lab0 != 0.0f) && (lab0 != -1.0f);
      fg1[k] = (lab1 != 0.0f) && (lab1 != -1.0f);

      // fast reciprocals for the bbox-target divides (rel err ~1e-7, harmless)
      float raw = __builtin_amdgcn_rcpf(aw), rah = __builtin_amdgcn_rcpf(ah);

      // ---- bbox smooth-L1 vs bbox_transform(anchor, matched gt) ----
      if (fg0[k]) {
        float mx1 = g0.z - 1.0f, my1 = g0.w - 1.0f;
        float gw = mx1 - g0.x + 1.0f, gh = my1 - g0.y + 1.0f;
        float gcx = g0.x + 0.5f * gw, gcy = g0.y + 0.5f * gh;
        float t0 = (gcx - acx) * raw, t1v = (gcy - acy) * rah;
        float t2 = logf(gw * raw), t3 = logf(gh * rah);
        t_bbox += huber9(d0 - t0) + huber9(d1 - t1v) + huber9(d2 - t2) + huber9(d3 - t3);
        t_nfg += 1.f;
      }
      if (fg1[k]) {
        float mx1 = g1.z - 1.0f, my1 = g1.w - 1.0f;
        float gw = mx1 - g1.x + 1.0f, gh = my1 - g1.y + 1.0f;
        float gcx = g1.x + 0.5f * gw, gcy = g1.y + 0.5f * gh;
        float t0 = (gcx - acx) * raw, t1v = (gcy - acy) * rah;
        float t2 = logf(gw * raw), t3 = logf(gh * rah);
        t_bbox += huber9(d4 - t0) + huber9(d5 - t1v) + huber9(d6 - t2) + huber9(d7 - t3);
        t_nfg += 1.f;
      }

      // ---- num softmax loss ----
      {
        int nl = ((lab0 > 0.f) ? 1 : 0) + ((lab1 > 0.f) ? 1 : 0) - 1;
        if (nl != -1) {
          float m = fmaxf(sn0, sn1);
          float lse = m + logf(expf(sn0 - m) + expf(sn1 - m));
          float picked = ((nl == 0) ? sn0 : sn1) - lse;
          t_num -= picked;
          t_ncnt += 1.f;
        }
      }

      // ---- enqueue for phase 2 (decoded-box argmaxes) only if fg ----
      needy[k] = fg0[k] || fg1[k];
      if (needy[k]) {
        // decode predicted boxes (identical expressions to the original)
        float p0cx = acx + d0 * aw, p0cy = acy + d1 * ah;
        float p0w = aw * expf(fminf(d2, BBOX_CLIP));
        float p0h = ah * expf(fminf(d3, BBOX_CLIP));
        float b0x0 = p0cx - 0.5f * p0w, b0y0 = p0cy - 0.5f * p0h;
        float b0x1 = p0cx + 0.5f * p0w, b0y1 = p0cy + 0.5f * p0h;
        float area0 = (b0x1 - b0x0 + 1.0f) * (b0y1 - b0y0 + 1.0f);

        float p1cx = acx + d4 * aw, p1cy = acy + d5 * ah;
        float p1w = aw * expf(fminf(d6, BBOX_CLIP));
        float p1h = ah * expf(fminf(d7, BBOX_CLIP));
        float b1x0 = p1cx - 0.5f * p1w, b1y0 = p1cy - 0.5f * p1h;
        float b1x1 = p1cx + 0.5f * p1w, b1y1 = p1cy + 0.5f * p1h;
        float area1 = (b1x1 - b1x0 + 1.0f) * (b1y1 - b1y0 + 1.0f);

        int slot = atomicAdd(&sNum, 1);
        sList[slot] = (unsigned char)(q + 64 * k);
        float* st = sStash[slot];
        st[0] = b0x0; st[1] = b0y0; st[2] = b0x1; st[3] = b0y1; st[4] = area0;
        st[5] = b1x0; st[6] = b1y0; st[7] = b1x1; st[8] = b1y1; st[9] = area1;
      }
    }
  }
  __syncthreads();

  // ---------------- phase 2: compacted decoded-box argmaxes ----------------
  {
    int num = sNum;               // uniform across block
    for (int sb = 0; sb < num; sb += 64) {
      int slot = sb + (threadIdx.x >> 2);
      int wseg = threadIdx.x & 3;
      if (slot < num) {   // uniform across each quad -> shfl butterfly safe
        const float* st = sStash[slot];
        float c0x0 = st[0], c0y0 = st[1], c0x1 = st[2], c0y1 = st[3], car0 = st[4];
        float c1x0 = st[5], c1y0 = st[6], c1x1 = st[7], c1y1 = st[8], car1 = st[9];
        float c0x1p = c0x1 + 1.0f, c0y1p = c0y1 + 1.0f;
        float c1x1p = c1x1 + 1.0f, c1y1p = c1y1 + 1.0f;

        uint32_t am = 0xFFFFFFFFu;                     // box 0 best
        uint32_t bk1 = 0xFFFFFFFFu, bk2 = 0xFFFFFFFFu; // box 1 best/2nd

        int g2 = wseg * len;
#pragma unroll 5
        for (int t = 0; t < len; ++t, ++g2) {
          float4 gb = sBox[g2];
          float ga = sA[g2];
          am = min(am, packKey(c0x0, c0y0, c0x1p, c0y1p, car0, gb, ga, (uint32_t)g2));
          uint32_t p = packKey(c1x0, c1y0, c1x1p, c1y1p, car1, gb, ga, (uint32_t)g2);
          uint32_t hib = max(p, bk1);
          bk1 = min(bk1, p);
          bk2 = min(bk2, hib);
        }

#pragma unroll
        for (int m = 1; m <= 2; m <<= 1) {
          am = min(am, (uint32_t)__shfl_xor((int)am, m, 64));
          uint32_t q1 = (uint32_t)__shfl_xor((int)bk1, m, 64);
          uint32_t q2 = (uint32_t)__shfl_xor((int)bk2, m, 64);
          uint32_t hib = max(bk1, q1);
          bk1 = min(bk1, q1);
          bk2 = min(min(bk2, q2), hib);
        }

        if (wseg == 0) {
          int pg1 = padG - 1;
          int ai  = min((int)(am  & 0x1FFu), pg1);
          int bi  = min((int)(bk1 & 0x1FFu), pg1);
          int bi2 = min((int)(bk2 & 0x1FFu), pg1);
          float4 ga4 = sBox[ai]; float aav = sA[ai];
          float aval = (aav < 1e29f) ? iouExact(c0x0, c0y0, c0x1, c0y1, car0, ga4, aav) : 0.0f;
          int bIdx = (ai == bi) ? bi2 : bi;  // b with b[ai] zeroed, then argmax
          float4 gb4 = sBox[bIdx]; float abv = sA[bIdx];
          float bval = (abv < 1e29f) ? iouExact(c1x0, c1y0, c1x1, c1y1, car1, gb4, abv) : 0.0f;
          sRes[sList[slot]] = make_float2(aval, bval);
        }
      }
    }
  }
  __syncthreads();

  // ---- IoU L1 loss (owner lane reads phase-2 results) ----
  if (seg == 0) {
#pragma unroll
    for (int k = 0; k < APQ; ++k) {
      if (needy[k]) {
        float2 r = sRes[q + 64 * k];
        if (fg0[k]) t_iou += fabsf(riv0[k] - r.x);
        if (fg1[k]) t_iou += fabsf(riv1[k] - fmaxf(r.y, 0.0f));
      }
    }
  }

  // block reduction: wave shuffle -> LDS -> one private record per block.
  // NO global atomics (same-line device-scope atomics serialized at ~114 us).
  float vals[7] = {t_cls, t_bbox, t_iou, t_num, t_npos, t_nfg, t_ncnt};
  int lane = threadIdx.x & 63;
  int wid = threadIdx.x >> 6;
#pragma unroll
  for (int k = 0; k < 7; ++k) {
    float s = waveSum(vals[k]);
    if (lane == 0) sRed[wid][k] = s;
  }
  __syncthreads();
  if (threadIdx.x < 7) {
    double s = (double)sRed[0][threadIdx.x] + (double)sRed[1][threadIdx.x] +
               (double)sRed[2][threadIdx.x] + (double)sRed[3][threadIdx.x];
    size_t bid = (size_t)blockIdx.y * gridDim.x + blockIdx.x;
    partial[bid * 8 + threadIdx.x] = s;    // 64-B record, no contention
  }
}

// Second dispatch on the same stream: kernel-boundary ordering makes the
// partial records visible. Sums nB x 7 doubles (~120 KB, L2-resident).
__global__ __launch_bounds__(1024) void retina_finalize(
    const double* __restrict__ partial, int nB, float* __restrict__ out) {
  __shared__ double sRed[16][7];
  double loc[7] = {0.0, 0.0, 0.0, 0.0, 0.0, 0.0, 0.0};
  for (int b = threadIdx.x; b < nB; b += 1024) {
    const double* r = partial + (size_t)b * 8;
#pragma unroll
    for (int k = 0; k < 7; ++k) loc[k] += r[k];
  }
  int lane = threadIdx.x & 63;
  int wid = threadIdx.x >> 6;
#pragma unroll
  for (int k = 0; k < 7; ++k) {
    double v = loc[k];
#pragma unroll
    for (int o = 32; o > 0; o >>= 1) v += __shfl_down(v, o, 64);
    if (lane == 0) sRed[wid][k] = v;
  }
  __syncthreads();
  if (threadIdx.x == 0) {
    double t[7];
#pragma unroll
    for (int k = 0; k < 7; ++k) {
      double s = 0.0;
      for (int w = 0; w < 16; ++w) s += sRed[w][k];
      t[k] = s;
    }
    double dpos = t[4] > 1.0 ? t[4] : 1.0;
    double dfg  = t[5] > 1.0 ? t[5] : 1.0;
    double dcnt = t[6] > 1.0 ? t[6] : 1.0;
    out[0] = (float)(t[0] / dpos);
    out[1] = (float)(2.0 * t[1] / dfg);
    out[2] = (float)(2.0 * t[2] / dfg);
    out[3] = (float)(t[3] / dcnt);
  }
}

extern "C" void kernel_launch(void* const* d_in, const int* in_sizes, int n_in,
                              void* d_out, int out_size, void* d_ws, size_t ws_size,
                              hipStream_t stream) {
  const float* pred_cls = (const float*)d_in[0];
  const float* rpn_num  = (const float*)d_in[1];
  const float* pred_reg = (const float*)d_in[2];
  const float* anchors  = (const float*)d_in[3];
  const float* rpn_iou  = (const float*)d_in[4];
  const float* boxes    = (const float*)d_in[5];
  // d_in[6] = im_info: unused by the reference math

  int A = in_sizes[3] / 4;
  int n = in_sizes[0] / (2 * A);
  int G = in_sizes[5] / (5 * n);

  double* partial = (double*)d_ws;  // (nB, 8) doubles = 64 B per block

  int nBx = (A + 127) / 128;        // 128 anchors per block (APQ=2)
  int nB = nBx * n;
  dim3 grid(nBx, n, 1);
  retina_main<<<grid, dim3(256, 1, 1), 0, stream>>>(
      pred_cls, rpn_num, pred_reg, anchors, rpn_iou, boxes,
      A, G, partial);
  retina_finalize<<<dim3(1, 1, 1), dim3(1024, 1, 1), 0, stream>>>(
      partial, nB, (float*)d_out);
}